// Round 17
// baseline (268.085 us; speedup 1.0000x reference)
//
#include <hip/hip_runtime.h>

// ---------------------------------------------------------------------------
// EMOGI ChebConv-K2 x3 : N=100000 nodes, E=800000 edges, dims 58->300->100->1
//   CSR by dst via PRIVATIZED histograms (8 copies; copy = edge-block & 7):
//     count: rank[i] = atomicAdd(&cntP[c][dst],1) ; atomicAdd(°P[c][src],1)
//     reduce: deg = sum degP -> dinv ; off8[c][n] = prefix of cntP -> cnt
//     scan -> rowstart ; fill: er[rowstart[d] + off8[c][d] + rank[i]]
//   (R16 theory: 1.6M atomics over 12.5K lines = ~128 serialized RMW/line;
//    8 copies cut per-line conflicts 8x.)
//   xb  [NR][128] bf16 = [x | p1 | 0]       (p1 filled by gather58)
//   k_mm12: FUSED  h1 = relu([x|p1]@W1+b1) (wave-private LDS stage) ;
//           ga2b[NR][208] = h1 @ [W21|pad|W20|pad]  (32-node waves)
//   gather_l2: p2 = prop(g2); h2 = relu(a2+p2+b2) in-reg; a3,g3 = h2@W3 dots
//   gather1: out = a3 + prop(g3)
// ---------------------------------------------------------------------------

typedef short bf16x8 __attribute__((ext_vector_type(8)));
typedef float f32x4 __attribute__((ext_vector_type(4)));

__device__ __forceinline__ unsigned f2bf(float f) {  // RNE fp32->bf16 bits
  unsigned u = __float_as_uint(f);
  u += 0x7fff + ((u >> 16) & 1);
  return u >> 16;
}
__device__ __forceinline__ float bf2f(unsigned s) {
  return __uint_as_float(s << 16);
}

// ---------------- fused CSR-count (privatized) + all preps ----------------
__global__ void k_count_prep(
    const int* __restrict__ src, const int* __restrict__ dst,
    unsigned* __restrict__ degP, unsigned* __restrict__ cntP,
    unsigned* __restrict__ rank, int E, int EB,
    const float* __restrict__ x, unsigned short* __restrict__ xb, int N, int XB,
    const float* __restrict__ W1, uint4* __restrict__ W1f,
    const float* __restrict__ W2, uint4* __restrict__ W2f,
    const float* __restrict__ b1, float* __restrict__ b1pad) {
  int b = blockIdx.x, t = threadIdx.x;
  if (b < EB) {
    int i = b * 256 + t;
    if (i < E) {
      size_t c = (size_t)(b & 7) * N;
      atomicAdd(&degP[c + src[i]], 1u);
      rank[i] = atomicAdd(&cntP[c + dst[i]], 1u);
    }
    return;
  }
  b -= EB;
  if (b < XB) {  // xb prep
    int idx = b * 256 + t;
    int n = idx >> 6, p = idx & 63;
    if (n >= N) return;
    int c = p * 2;
    if (c < 58) {
      unsigned lo = f2bf(x[(size_t)n * 58 + c]);
      unsigned hi = f2bf(x[(size_t)n * 58 + c + 1]);
      *(unsigned*)(xb + (size_t)n * 128 + c) = lo | (hi << 16);
    } else if (c >= 116) {
      *(unsigned*)(xb + (size_t)n * 128 + c) = 0;
    }
    return;
  }
  b -= XB;
  if (b < 20) {  // W1f fragment pack [s<4][j<20][lane<64][8 bf16]
    int idx = b * 256 + t;
    int lane = idx & 63, j = (idx >> 6) % 20, s = (idx >> 6) / 20;
    int lr = lane & 15, g = lane >> 4;
    int c = j * 16 + lr;
    unsigned short v[8];
#pragma unroll
    for (int i = 0; i < 8; i++) {
      int k = s * 32 + g * 8 + i;
      float f = 0.0f;
      if (c < 300 && k < 116)
        f = (k < 58) ? W1[k * 300 + c] : W1[17400 + (k - 58) * 300 + c];
      v[i] = (unsigned short)f2bf(f);
    }
    W1f[idx] = *(const uint4*)v;
    return;
  }
  b -= 20;
  if (b < 33) {  // W2f fragment pack [s<10][j<13][lane<64][8 bf16]
    int idx = b * 256 + t;
    if (idx >= 10 * 13 * 64) return;
    int lane = idx & 63, j = (idx >> 6) % 13, s = (idx >> 6) / 13;
    int lr = lane & 15, g = lane >> 4;
    int r = j * 16 + lr;
    unsigned short v[8];
#pragma unroll
    for (int i = 0; i < 8; i++) {
      int k = s * 32 + g * 8 + i;
      float f = 0.0f;
      if (k < 300) {
        if (r < 100) f = W2[30000 + k * 100 + r];
        else if (r >= 104 && r < 204) f = W2[k * 100 + (r - 104)];
      }
      v[i] = (unsigned short)f2bf(f);
    }
    W2f[idx] = *(const uint4*)v;
    return;
  }
  b -= 33;
  {  // b1pad (2 blocks)
    int idx = b * 256 + t;
    if (idx < 320) b1pad[idx] = (idx < 300) ? b1[idx] : 0.0f;
  }
}

// reduce 8 copies: dinv from deg sum; off8[c][n] = prefix of cntP; cnt = total
__global__ void k_reduce(const unsigned* __restrict__ degP,
                         const unsigned* __restrict__ cntP,
                         float* __restrict__ dinv, unsigned* __restrict__ cnt,
                         unsigned* __restrict__ off8, int N) {
  int n = blockIdx.x * blockDim.x + threadIdx.x;
  if (n >= N) return;
  unsigned d = 0;
#pragma unroll
  for (int c = 0; c < 8; c++) d += degP[(size_t)c * N + n];
  dinv[n] = d ? rsqrtf((float)d) : 0.0f;
  unsigned acc = 0;
#pragma unroll
  for (int c = 0; c < 8; c++) {
    off8[(size_t)c * N + n] = acc;
    acc += cntP[(size_t)c * N + n];
  }
  cnt[n] = acc;
}

__global__ __launch_bounds__(256) void k_scan1(const unsigned* __restrict__ cnt,
                                               unsigned* __restrict__ btot, int N) {
  __shared__ unsigned s[256];
  int b = blockIdx.x, t = threadIdx.x;
  int base = b * 1024;
  unsigned sum = 0;
  for (int i = t; i < 1024; i += 256) {
    int idx = base + i;
    sum += (idx < N) ? cnt[idx] : 0u;
  }
  s[t] = sum;
  __syncthreads();
  for (int off = 128; off > 0; off >>= 1) {
    if (t < off) s[t] += s[t + off];
    __syncthreads();
  }
  if (t == 0) btot[b] = s[0];
}

__global__ __launch_bounds__(256) void k_scan2(unsigned* __restrict__ btot,
                                               unsigned* __restrict__ rowstart,
                                               int NB, int N, int E) {
  __shared__ unsigned s[256];
  int t = threadIdx.x;
  s[t] = (t < NB) ? btot[t] : 0u;
  __syncthreads();
  if (t == 0) {
    unsigned acc = 0;
    for (int i = 0; i < NB; i++) { unsigned v = s[i]; s[i] = acc; acc += v; }
  }
  __syncthreads();
  if (t < NB) btot[t] = s[t];
  if (t == 0) rowstart[N] = (unsigned)E;
}

__global__ __launch_bounds__(256) void k_scan3(const unsigned* __restrict__ cnt,
                                               const unsigned* __restrict__ btot,
                                               unsigned* __restrict__ rowstart, int N) {
  __shared__ unsigned ssum[256];
  int b = blockIdx.x, t = threadIdx.x;
  int base = b * 1024 + t * 4;
  unsigned v0 = 0, v1 = 0, v2 = 0, v3 = 0;
  if (base + 0 < N) v0 = cnt[base + 0];
  if (base + 1 < N) v1 = cnt[base + 1];
  if (base + 2 < N) v2 = cnt[base + 2];
  if (base + 3 < N) v3 = cnt[base + 3];
  ssum[t] = v0 + v1 + v2 + v3;
  __syncthreads();
  for (int off = 1; off < 256; off <<= 1) {
    unsigned add = (t >= off) ? ssum[t - off] : 0u;
    __syncthreads();
    ssum[t] += add;
    __syncthreads();
  }
  unsigned texcl = ((t == 0) ? 0u : ssum[t - 1]) + btot[b];
  unsigned r0 = texcl, r1 = r0 + v0, r2 = r1 + v1, r3 = r2 + v2;
  if (base + 0 < N) rowstart[base + 0] = r0;
  if (base + 1 < N) rowstart[base + 1] = r1;
  if (base + 2 < N) rowstart[base + 2] = r2;
  if (base + 3 < N) rowstart[base + 3] = r3;
}

// fill: position = rowstart[dst] + off8[copy][dst] + rank  (copy = blk&7)
__global__ void k_fill(const int* __restrict__ src, const int* __restrict__ dst,
                       const float* __restrict__ dinv, const unsigned* __restrict__ rowstart,
                       const unsigned* __restrict__ off8, const unsigned* __restrict__ rank,
                       int2* __restrict__ er, int E, int N) {
  int e = blockIdx.x * blockDim.x + threadIdx.x;
  if (e >= E) return;
  int s = src[e], d = dst[e];
  size_t c = (size_t)((e >> 8) & 7) * N;
  er[rowstart[d] + off8[c + d] + rank[e]] = make_int2(s, __float_as_int(dinv[s]));
}

// ---------------- gathers (8-wide masked MLP) ----------------
__global__ __launch_bounds__(256) void k_gather58(
    const unsigned* __restrict__ rowstart, const int2* __restrict__ er,
    const float* __restrict__ dinv, unsigned short* __restrict__ xb, int N) {
  int pair = (blockIdx.x * blockDim.x + threadIdx.x) >> 6;
  int lane = threadIdx.x & 63;
  int wid = pair * 2 + (lane >> 5);
  int c0 = (lane & 31) * 2;
  if (wid >= N || c0 >= 58) return;
  unsigned s0 = rowstart[wid], s1 = rowstart[wid + 1];
  float a0[8], a1[8];
#pragma unroll
  for (int k = 0; k < 8; k++) { a0[k] = 0.f; a1[k] = 0.f; }
  for (unsigned e = s0; e < s1; e += 8) {
    int2 r[8];
#pragma unroll
    for (int k = 0; k < 8; k++) {
      unsigned idx = e + k;
      r[k] = er[idx < s1 ? idx : s1 - 1];
    }
    unsigned v[8];
#pragma unroll
    for (int k = 0; k < 8; k++)
      v[k] = *(const unsigned*)(xb + (size_t)r[k].x * 128 + c0);
#pragma unroll
    for (int k = 0; k < 8; k++) {
      float w = (e + k < s1) ? __int_as_float(r[k].y) : 0.f;
      a0[k] += w * bf2f(v[k] & 0xffffu);
      a1[k] += w * bf2f(v[k] >> 16);
    }
  }
  float dd = -dinv[wid];
  float p0 = dd * (((a0[0] + a0[1]) + (a0[2] + a0[3])) + ((a0[4] + a0[5]) + (a0[6] + a0[7])));
  float p1 = dd * (((a1[0] + a1[1]) + (a1[2] + a1[3])) + ((a1[4] + a1[5]) + (a1[6] + a1[7])));
  *(unsigned*)(xb + (size_t)wid * 128 + 58 + c0) = f2bf(p0) | (f2bf(p1) << 16);
}

__global__ __launch_bounds__(256) void k_gather_l2(
    const unsigned* __restrict__ rowstart, const int2* __restrict__ er,
    const float* __restrict__ dinv, const unsigned short* __restrict__ ga2b,
    const float* __restrict__ b2, const float* __restrict__ W30,
    const float* __restrict__ W31, const float* __restrict__ b3,
    float* __restrict__ a3, float* __restrict__ g3, int N) {
  int wid = (blockIdx.x * blockDim.x + threadIdx.x) >> 6;
  if (wid >= N) return;
  int lane = threadIdx.x & 63;
  int c0 = lane * 2;
  bool act = c0 < 100;
  unsigned s0 = rowstart[wid], s1 = rowstart[wid + 1];
  float aa = 0.f, gg = 0.f;
  if (act) {
    float a0[8], a1[8];
#pragma unroll
    for (int k = 0; k < 8; k++) { a0[k] = 0.f; a1[k] = 0.f; }
    for (unsigned e = s0; e < s1; e += 8) {
      int2 r[8];
#pragma unroll
      for (int k = 0; k < 8; k++) {
        unsigned idx = e + k;
        r[k] = er[idx < s1 ? idx : s1 - 1];
      }
      unsigned v[8];
#pragma unroll
      for (int k = 0; k < 8; k++)
        v[k] = *(const unsigned*)(ga2b + (size_t)r[k].x * 208 + c0);
#pragma unroll
      for (int k = 0; k < 8; k++) {
        float w = (e + k < s1) ? __int_as_float(r[k].y) : 0.f;
        a0[k] += w * bf2f(v[k] & 0xffffu);
        a1[k] += w * bf2f(v[k] >> 16);
      }
    }
    float dd = -dinv[wid];
    float p0 = dd * (((a0[0] + a0[1]) + (a0[2] + a0[3])) + ((a0[4] + a0[5]) + (a0[6] + a0[7])));
    float p1 = dd * (((a1[0] + a1[1]) + (a1[2] + a1[3])) + ((a1[4] + a1[5]) + (a1[6] + a1[7])));
    unsigned av = *(const unsigned*)(ga2b + (size_t)wid * 208 + 104 + c0);
    float h0 = fmaxf(bf2f(av & 0xffffu) + p0 + b2[c0], 0.f);
    float h1 = fmaxf(bf2f(av >> 16) + p1 + b2[c0 + 1], 0.f);
    aa = h0 * W30[c0] + h1 * W30[c0 + 1];
    gg = h0 * W31[c0] + h1 * W31[c0 + 1];
  }
#pragma unroll
  for (int off = 32; off > 0; off >>= 1) {
    aa += __shfl_xor(aa, off);
    gg += __shfl_xor(gg, off);
  }
  if (lane == 0) {
    a3[wid] = aa + b3[0];
    g3[wid] = gg;
  }
}

__global__ void k_gather1(const unsigned* __restrict__ rowstart, const int2* __restrict__ er,
                          const float* __restrict__ dinv, const float* __restrict__ g3,
                          const float* __restrict__ a3, float* __restrict__ out, int N) {
  int n = blockIdx.x * blockDim.x + threadIdx.x;
  if (n >= N) return;
  unsigned s0 = rowstart[n], s1 = rowstart[n + 1];
  float a[8];
#pragma unroll
  for (int k = 0; k < 8; k++) a[k] = 0.f;
  for (unsigned e = s0; e < s1; e += 8) {
    int2 r[8];
#pragma unroll
    for (int k = 0; k < 8; k++) {
      unsigned idx = e + k;
      r[k] = er[idx < s1 ? idx : s1 - 1];
    }
    float gv[8];
#pragma unroll
    for (int k = 0; k < 8; k++) gv[k] = g3[r[k].x];
#pragma unroll
    for (int k = 0; k < 8; k++) {
      float w = (e + k < s1) ? __int_as_float(r[k].y) : 0.f;
      a[k] += w * gv[k];
    }
  }
  float sum = ((a[0] + a[1]) + (a[2] + a[3])) + ((a[4] + a[5]) + (a[6] + a[7]));
  out[n] = a3[n] - dinv[n] * sum;
}

// ---------------- FUSED MFMA layer1+layer2 (32-node waves) ------------------
#define STG 324  // 648B row stride
__global__ __launch_bounds__(128, 2) void k_mm12_mfma(
    const unsigned short* __restrict__ xb, const uint4* __restrict__ W1f,
    const uint4* __restrict__ W2f, const float* __restrict__ b1pad,
    unsigned short* __restrict__ ga2b) {
  __shared__ unsigned short stage[2 * 32 * STG];  // 41.5 KB
  int tid = threadIdx.x;
  int lane = tid & 63, wv = tid >> 6, lr = lane & 15, g = lane >> 4;
  int n0 = blockIdx.x * 64 + wv * 32;
  unsigned short* ost = stage + wv * 32 * STG;

  // ---- mm1: two 10-j halves, two node sub-tiles ----
  bf16x8 a1[2][4];
#pragma unroll
  for (int t = 0; t < 2; t++)
#pragma unroll
    for (int s = 0; s < 4; s++)
      a1[t][s] = *(const bf16x8*)(xb + (size_t)(n0 + t * 16 + lr) * 128 + s * 32 + g * 8);
#pragma unroll
  for (int half = 0; half < 2; half++) {
    f32x4 acc[2][10];
#pragma unroll
    for (int t = 0; t < 2; t++)
#pragma unroll
      for (int j = 0; j < 10; j++) acc[t][j] = (f32x4){0.f, 0.f, 0.f, 0.f};
#pragma unroll
    for (int s = 0; s < 4; s++) {
      bf16x8 w[10];
#pragma unroll
      for (int j = 0; j < 10; j++)
        w[j] = *(const bf16x8*)&W1f[(s * 20 + half * 10 + j) * 64 + lane];
      __builtin_amdgcn_sched_barrier(0);  // all 10 loads before any mfma
#pragma unroll
      for (int j = 0; j < 10; j++) {
        acc[0][j] = __builtin_amdgcn_mfma_f32_16x16x32_bf16(w[j], a1[0][s], acc[0][j], 0, 0, 0);
        acc[1][j] = __builtin_amdgcn_mfma_f32_16x16x32_bf16(w[j], a1[1][s], acc[1][j], 0, 0, 0);
      }
    }
#pragma unroll
    for (int t = 0; t < 2; t++)
#pragma unroll
      for (int j = 0; j < 10; j++) {
        int c = half * 160 + j * 16 + g * 4;
        float4 bv = *(const float4*)(b1pad + c);
        unsigned lo = f2bf(fmaxf(acc[t][j][0] + bv.x, 0.f)) |
                      (f2bf(fmaxf(acc[t][j][1] + bv.y, 0.f)) << 16);
        unsigned hi = f2bf(fmaxf(acc[t][j][2] + bv.z, 0.f)) |
                      (f2bf(fmaxf(acc[t][j][3] + bv.w, 0.f)) << 16);
        uint2 pk; pk.x = lo; pk.y = hi;
        *(uint2*)(ost + (t * 16 + lr) * STG + c) = pk;
      }
  }

  // ---- mm2: chunk0 j 0-6, chunk1 j 7-12; outputs held packed in regs ----
  uint2 pk0[2][7], pk1[2][6];
  {
    f32x4 acc[2][7];
#pragma unroll
    for (int t = 0; t < 2; t++)
#pragma unroll
      for (int j = 0; j < 7; j++) acc[t][j] = (f32x4){0.f, 0.f, 0.f, 0.f};
#pragma unroll
    for (int s = 0; s < 10; s++) {
      bf16x8 a0 = *(const bf16x8*)(ost + lr * STG + s * 32 + g * 8);
      bf16x8 a1v = *(const bf16x8*)(ost + (16 + lr) * STG + s * 32 + g * 8);
      bf16x8 w[7];
#pragma unroll
      for (int j = 0; j < 7; j++) w[j] = *(const bf16x8*)&W2f[(s * 13 + j) * 64 + lane];
      __builtin_amdgcn_sched_barrier(0);
#pragma unroll
      for (int j = 0; j < 7; j++) {
        acc[0][j] = __builtin_amdgcn_mfma_f32_16x16x32_bf16(w[j], a0, acc[0][j], 0, 0, 0);
        acc[1][j] = __builtin_amdgcn_mfma_f32_16x16x32_bf16(w[j], a1v, acc[1][j], 0, 0, 0);
      }
    }
#pragma unroll
    for (int t = 0; t < 2; t++)
#pragma unroll
      for (int j = 0; j < 7; j++) {
        pk0[t][j].x = f2bf(acc[t][j][0]) | (f2bf(acc[t][j][1]) << 16);
        pk0[t][j].y = f2bf(acc[t][j][2]) | (f2bf(acc[t][j][3]) << 16);
      }
  }
  {
    f32x4 acc[2][6];
#pragma unroll
    for (int t = 0; t < 2; t++)
#pragma unroll
      for (int j = 0; j < 6; j++) acc[t][j] = (f32x4){0.f, 0.f, 0.f, 0.f};
#pragma unroll
    for (int s = 0; s < 10; s++) {
      bf16x8 a0 = *(const bf16x8*)(ost + lr * STG + s * 32 + g * 8);
      bf16x8 a1v = *(const bf16x8*)(ost + (16 + lr) * STG + s * 32 + g * 8);
      bf16x8 w[6];
#pragma unroll
      for (int j = 0; j < 6; j++) w[j] = *(const bf16x8*)&W2f[(s * 13 + 7 + j) * 64 + lane];
      __builtin_amdgcn_sched_barrier(0);
#pragma unroll
      for (int j = 0; j < 6; j++) {
        acc[0][j] = __builtin_amdgcn_mfma_f32_16x16x32_bf16(w[j], a0, acc[0][j], 0, 0, 0);
        acc[1][j] = __builtin_amdgcn_mfma_f32_16x16x32_bf16(w[j], a1v, acc[1][j], 0, 0, 0);
      }
    }
#pragma unroll
    for (int t = 0; t < 2; t++)
#pragma unroll
      for (int j = 0; j < 6; j++) {
        pk1[t][j].x = f2bf(acc[t][j][0]) | (f2bf(acc[t][j][1]) << 16);
        pk1[t][j].y = f2bf(acc[t][j][2]) | (f2bf(acc[t][j][3]) << 16);
      }
  }
  // out epilogue: all h1 stage reads done; reuse stage as [32][216]
#pragma unroll
  for (int t = 0; t < 2; t++) {
#pragma unroll
    for (int j = 0; j < 7; j++)
      *(uint2*)(ost + (t * 16 + lr) * 216 + j * 16 + g * 4) = pk0[t][j];
#pragma unroll
    for (int j = 0; j < 6; j++)
      *(uint2*)(ost + (t * 16 + lr) * 216 + (7 + j) * 16 + g * 4) = pk1[t][j];
  }
  // wave tile rows n0..n0+31 x 208 cols = 13312 contiguous bytes
  uint4* gdst = (uint4*)(ga2b + (size_t)n0 * 208);
  for (int idx = lane; idx < 832; idx += 64) {
    int row = idx / 26, q = idx - row * 26;
    gdst[idx] = *(const uint4*)(ost + row * 216 + q * 8);
  }
}

// ---------------- launch ----------------
extern "C" void kernel_launch(void* const* d_in, const int* in_sizes, int n_in,
                              void* d_out, int out_size, void* d_ws, size_t ws_size,
                              hipStream_t stream) {
  const float* x  = (const float*)d_in[0];
  const int*   ei = (const int*)d_in[1];
  const float* W1 = (const float*)d_in[2];  // [2][58][300]
  const float* b1 = (const float*)d_in[3];
  const float* W2 = (const float*)d_in[4];  // [2][300][100]
  const float* b2 = (const float*)d_in[5];
  const float* W3 = (const float*)d_in[6];  // [2][100][1]
  const float* b3 = (const float*)d_in[7];
  float* out = (float*)d_out;

  const int N = in_sizes[0] / 58;            // 100000
  const int E = in_sizes[1] / 2;             // 800000
  const int NR = (N + 127) & ~127;           // 100096 (multiple of 64)
  const int NB = (N + 1023) / 1024;
  const int* src = ei;
  const int* dst = ei + E;

  char* ws = (char*)d_ws;
  size_t off = 0;
  auto alloc = [&](size_t bytes) -> void* {
    void* p = ws + off;
    off += (bytes + 255) & ~(size_t)255;
    return p;
  };
  unsigned* degP     = (unsigned*)alloc((size_t)16 * N * 4);  // degP[8]|cntP[8]
  unsigned* cntP     = degP + (size_t)8 * N;
  unsigned* off8     = (unsigned*)alloc((size_t)8 * N * 4);
  unsigned* cnt      = (unsigned*)alloc((size_t)N * 4);
  float*    dinv     = (float*)alloc((size_t)N * 4);
  unsigned* rowstart = (unsigned*)alloc((size_t)(N + 1) * 4);
  unsigned* rank     = (unsigned*)alloc((size_t)E * 4);
  unsigned* btot     = (unsigned*)alloc((size_t)256 * 4);
  int2*     er       = (int2*)alloc((size_t)E * 8);
  unsigned short* xb   = (unsigned short*)alloc((size_t)NR * 128 * 2);
  uint4*    W1f      = (uint4*)alloc((size_t)4 * 20 * 64 * 16);   // 80 KB
  uint4*    W2f      = (uint4*)alloc((size_t)10 * 13 * 64 * 16);  // 133 KB
  float*    b1pad    = (float*)alloc((size_t)320 * 4);
  unsigned short* ga2b = (unsigned short*)alloc((size_t)NR * 208 * 2);
  float* a3 = (float*)alloc((size_t)N * 4);
  float* g3 = (float*)alloc((size_t)N * 4);

  const int EB = (E + 255) / 256;            // 3125 edge blocks
  const int XB = ((size_t)N * 64 + 255) / 256;  // 25000 xb blocks

  // --- CSR count (privatized) + ALL preps fused ---
  hipMemsetAsync(degP, 0, (size_t)16 * N * 4, stream);
  k_count_prep<<<EB + XB + 20 + 33 + 2, 256, 0, stream>>>(
      src, dst, degP, cntP, rank, E, EB, x, xb, N, XB, W1, W1f, W2, W2f, b1, b1pad);
  k_reduce<<<(N + 255) / 256, 256, 0, stream>>>(degP, cntP, dinv, cnt, off8, N);
  k_scan1<<<NB, 256, 0, stream>>>(cnt, btot, N);
  k_scan2<<<1, 256, 0, stream>>>(btot, rowstart, NB, N, E);
  k_scan3<<<NB, 256, 0, stream>>>(cnt, btot, rowstart, N);
  k_fill<<<(E + 255) / 256, 256, 0, stream>>>(src, dst, dinv, rowstart, off8, rank, er, E, N);

  // --- layer 1+2 fused ---
  k_gather58<<<((N + 1) / 2 * 64 + 255) / 256, 256, 0, stream>>>(rowstart, er, dinv, xb, N);
  k_mm12_mfma<<<NR / 64, 128, 0, stream>>>(xb, W1f, W2f, b1pad, ga2b);
  k_gather_l2<<<(N + 3) / 4, 256, 0, stream>>>(rowstart, er, dinv, ga2b,
                                               b2, W3, W3 + 100, b3, a3, g3, N);

  // --- layer 3 ---
  k_gather1<<<(N + 255) / 256, 256, 0, stream>>>(rowstart, er, dinv, g3, a3, out, N);
}